// Round 22
// baseline (66.443 us; speedup 1.0000x reference)
//
#include <hip/hip_runtime.h>

#define BB 8192
#define TT 2048
#define CLW 16   // window length; one lane = one 16-step window; one wave = half a row
#define WU  8    // h warmup steps: contraction ~0.4/step -> h err ~7e-4, out err ~3e-4
// LDS: TWO regions per wave, each [32 rows x 33 words] (two 16-step windows per row,
// verified conflict-free: write 2/bank free, float4 readback 2/bank free).
//   r0: f16x2(pg,cg)  -> f32 corrects (overwritten in epilogue) -> transposed store
//   r1: f16x2(A,B)    -> f32 latents  (overwritten in phase 2)  -> transposed store
// This moves A[16]/B[16] out of registers: live set ~60 -> ~40, so a declared
// bound of 5 (cap ~51) raises residency WITHOUT the R20 spill (cap40 < live60).

typedef __fp16 f16x2 __attribute__((ext_vector_type(2)));

__device__ __forceinline__ float sig2(float z) {
    return __builtin_amdgcn_rcpf(1.f + __builtin_amdgcn_exp2f(z));
}
__device__ __forceinline__ float sgpr(float v) {
    return __builtin_bit_cast(float, __builtin_amdgcn_readfirstlane(__builtin_bit_cast(int, v)));
}
__device__ __forceinline__ void ld16(float* d, const float* p) {
    *(float4*)(d)      = *(const float4*)(p);
    *(float4*)(d + 4)  = *(const float4*)(p + 4);
    *(float4*)(d + 8)  = *(const float4*)(p + 8);
    *(float4*)(d + 12) = *(const float4*)(p + 12);
}

// Residency ladder (measured): bound3/4 -> occ 34%, 64-66us, clean; bound6 -> occ
// 52% but cap40 < live60 -> spill, 87us; bound8 -> full spill, 166us. cap(N)~256/N.
// Bound 5 -> cap ~51 >= new live set ~40: raise residency, stay under spill line.
__global__ __launch_bounds__(256, 5) void bkt_fused(
    const float* __restrict__ x, const float* __restrict__ y,
    const float* __restrict__ Wxh, const float* __restrict__ Whh,
    const float* __restrict__ bh, const float* __restrict__ Wy,
    const float* __restrict__ by, const float* __restrict__ prior,
    float* __restrict__ corrects, float* __restrict__ latents,
    float* __restrict__ partials)
{
    __shared__ float lds[4 * 2 * 32 * 33];             // 33.8 KB: 2 regions per wave
    __shared__ float2 hand[2];                         // per-row (A,B) handoff
    const int tid  = blockIdx.x * 256 + threadIdx.x;
    const int lane = threadIdx.x & 63;
    const int wv   = threadIdx.x >> 6;                 // 0..3
    const int half = wv & 1;                           // which half-row
    const int rib  = wv >> 1;                          // row in block (0..1)
    const int row  = blockIdx.x * 2 + rib;
    float* r0 = &lds[wv * 2112];                       // pg/cg -> corrects
    float* r1 = r0 + 1056;                             // A/B   -> latents
    const int wbase = (lane >> 1) * 33 + (lane & 1) * 16;   // this window's LDS base
    const float NL2E = -1.44269504088896340736f;

    // ---- weights -> SGPRs, pre-scaled for exp2-based sigmoid ----
    const float wh00=sgpr(Whh[0]*NL2E),  wh01=sgpr(Whh[1]*NL2E),
                wh02=sgpr(Whh[2]*NL2E),  wh03=sgpr(Whh[3]*NL2E),
                wh10=sgpr(Whh[4]*NL2E),  wh11=sgpr(Whh[5]*NL2E),
                wh12=sgpr(Whh[6]*NL2E),  wh13=sgpr(Whh[7]*NL2E),
                wh20=sgpr(Whh[8]*NL2E),  wh21=sgpr(Whh[9]*NL2E),
                wh22=sgpr(Whh[10]*NL2E), wh23=sgpr(Whh[11]*NL2E),
                wh30=sgpr(Whh[12]*NL2E), wh31=sgpr(Whh[13]*NL2E),
                wh32=sgpr(Whh[14]*NL2E), wh33=sgpr(Whh[15]*NL2E);
    const float wx0=sgpr(Wxh[0]*NL2E), wx1=sgpr(Wxh[1]*NL2E),
                wx2=sgpr(Wxh[2]*NL2E), wx3=sgpr(Wxh[3]*NL2E);
    const float bh0=sgpr(bh[0]*NL2E), bh1=sgpr(bh[1]*NL2E),
                bh2=sgpr(bh[2]*NL2E), bh3=sgpr(bh[3]*NL2E);
    const float wy00=sgpr(Wy[0]*NL2E),  wy01=sgpr(Wy[1]*NL2E),
                wy02=sgpr(Wy[2]*NL2E),  wy03=sgpr(Wy[3]*NL2E),
                wy10=sgpr(Wy[4]*NL2E),  wy11=sgpr(Wy[5]*NL2E),
                wy12=sgpr(Wy[6]*NL2E),  wy13=sgpr(Wy[7]*NL2E),
                wy20=sgpr(Wy[8]*NL2E),  wy21=sgpr(Wy[9]*NL2E),
                wy22=sgpr(Wy[10]*NL2E), wy23=sgpr(Wy[11]*NL2E),
                wy30=sgpr(Wy[12]*NL2E), wy31=sgpr(Wy[13]*NL2E),
                wy32=sgpr(Wy[14]*NL2E), wy33=sgpr(Wy[15]*NL2E);
    const float by0=sgpr(by[0]*NL2E), by1=sgpr(by[1]*NL2E),
                by2=sgpr(by[2]*NL2E), by3=sgpr(by[3]*NL2E);
    const float pr = sgpr(prior[0]);

#define HSTEP(xs)                                                                   \
    {                                                                               \
        float z0 = fmaf(h3,wh30,fmaf(h2,wh20,fmaf(h1,wh10,fmaf(h0,wh00,fmaf(xs,wx0,bh0))))); \
        float z1 = fmaf(h3,wh31,fmaf(h2,wh21,fmaf(h1,wh11,fmaf(h0,wh01,fmaf(xs,wx1,bh1))))); \
        float z2 = fmaf(h3,wh32,fmaf(h2,wh22,fmaf(h1,wh12,fmaf(h0,wh02,fmaf(xs,wx2,bh2))))); \
        float z3 = fmaf(h3,wh33,fmaf(h2,wh23,fmaf(h1,wh13,fmaf(h0,wh03,fmaf(xs,wx3,bh3))))); \
        h0 = sig2(z0); h1 = sig2(z1); h2 = sig2(z2); h3 = sig2(z3);                 \
    }

    const int c  = half * 64 + lane;                   // window id within row
    const int t0 = c * CLW;
    const float* xrow = x + (size_t)row * TT;
    float* crow = corrects + (size_t)row * TT + half * 1024;
    float* lrow = latents  + (size_t)row * TT + half * 1024;

    // ---- x loads up front (t0-8 is 32B-aligned) ----
    float xw[8], xb[16];
    {
        const float* wp = xrow + (c ? t0 - WU : 0);
        *(float4*)(xw)     = *(const float4*)(wp);
        *(float4*)(xw + 4) = *(const float4*)(wp + 4);
    }
    ld16(xb, xrow + t0);

    // ---- warmup: 8 HSTEPs (window 0 resets to exact h=0) ----
    float h0 = 0.f, h1 = 0.f, h2 = 0.f, h3 = 0.f;
    HSTEP(xw[0])  HSTEP(xw[1])  HSTEP(xw[2])  HSTEP(xw[3])
    HSTEP(xw[4])  HSTEP(xw[5])  HSTEP(xw[6])  HSTEP(xw[7])
    if (c == 0) { h0 = h1 = h2 = h3 = 0.f; }

    // ---- single pass: sigmoids -> running (A,B) packed f16x2 -> r1;
    //      (pg,cg) packed f16x2 -> r0. No coefficient arrays in registers. ----
    float Aacc = 1.f, Bacc = 0.f;
#define S1(s, DO_H)                                                                 \
    {                                                                               \
        float zl = fmaf(h3,wy30,fmaf(h2,wy20,fmaf(h1,wy10,fmaf(h0,wy00,by0))));     \
        float zf = fmaf(h3,wy31,fmaf(h2,wy21,fmaf(h1,wy11,fmaf(h0,wy01,by1))));     \
        float zg = fmaf(h3,wy32,fmaf(h2,wy22,fmaf(h1,wy12,fmaf(h0,wy02,by2))));     \
        float zs = fmaf(h3,wy33,fmaf(h2,wy23,fmaf(h1,wy13,fmaf(h0,wy03,by3))));     \
        float pl = sig2(zl), pf = sig2(zf), pgs = sig2(zg), pss = sig2(zs);         \
        float a = (1.f - pf) - pl;                                                  \
        Bacc = fmaf(a, Bacc, pl);                                                   \
        Aacc *= a;                                                                  \
        f16x2 pk0 = __builtin_amdgcn_cvt_pkrtz(pgs, (1.f - pss) - pgs);             \
        f16x2 pk1 = __builtin_amdgcn_cvt_pkrtz(Aacc, Bacc);                         \
        r0[wbase + (s)] = __builtin_bit_cast(float, pk0);                           \
        r1[wbase + (s)] = __builtin_bit_cast(float, pk1);                           \
        DO_H                                                                        \
    }
    S1(0,  HSTEP(xb[0]))  S1(1,  HSTEP(xb[1]))  S1(2,  HSTEP(xb[2]))
    S1(3,  HSTEP(xb[3]))  S1(4,  HSTEP(xb[4]))  S1(5,  HSTEP(xb[5]))
    S1(6,  HSTEP(xb[6]))  S1(7,  HSTEP(xb[7]))  S1(8,  HSTEP(xb[8]))
    S1(9,  HSTEP(xb[9]))  S1(10, HSTEP(xb[10])) S1(11, HSTEP(xb[11]))
    S1(12, HSTEP(xb[12])) S1(13, HSTEP(xb[13])) S1(14, HSTEP(xb[14]))
    S1(15, )                                          // last h never consumed
#undef S1

    // ---- y load (covered by scan+sync latency) ----
    float yb[16];
    ld16(yb, y + (size_t)row * TT + t0);

    // ---- in-wave inclusive scan of window maps (f32 accumulators) ----
    float As = Aacc, Bs = Bacc;
#pragma unroll
    for (int off = 1; off < 64; off <<= 1) {
        float Au = __shfl_up(As, off);
        float Bu = __shfl_up(Bs, off);
        if (lane >= off) { Bs = fmaf(As, Bu, Bs); As *= Au; }
    }
    // cross-wave handoff: half-0 total -> half-1 prior
    if (half == 0 && lane == 63) hand[rib] = make_float2(As, Bs);
    __syncthreads();
    float pr_base = pr;
    if (half) { const float2 hv = hand[rib]; pr_base = fmaf(hv.x, pr, hv.y); }
    const float Ae = __shfl_up(As, 1);
    const float Be = __shfl_up(Bs, 1);
    const float lat0 = (lane == 0) ? pr_base : fmaf(Ae, pr_base, Be);

    // ---- epilogue phase 1: unpack coeffs, compute c, overwrite r0 with f32 c ----
    float lacc = 0.f, prod = 1.f, latp = lat0;
#define E(s)                                                                        \
    {                                                                               \
        f16x2 pk0 = __builtin_bit_cast(f16x2, r0[wbase + (s)]);                     \
        f16x2 pk1 = __builtin_bit_cast(f16x2, r1[wbase + (s)]);                     \
        float cv = fmaf(latp, (float)pk0[1], (float)pk0[0]);                        \
        latp = fmaf((float)pk1[0], lat0, (float)pk1[1]);                            \
        float cc  = fminf(fmaxf(cv, 1e-7f), 1.f - 1e-7f);                           \
        prod *= fmaf(yb[s], fmaf(2.f, cc, -1.f), 1.f - cc);                         \
        r0[wbase + (s)] = cv;                                                       \
    }
    E(0) E(1) E(2) E(3) E(4) E(5) E(6) E(7)
    lacc += __builtin_amdgcn_logf(prod); prod = 1.f;
    E(8) E(9) E(10) E(11) E(12) E(13) E(14) E(15)
    lacc += __builtin_amdgcn_logf(prod);
#undef E

    // ---- corrects: transposed readback (2/bank = free);
    //      each global store instr = contiguous 1 KB ----
#pragma unroll
    for (int j = 0; j < 4; ++j) {
        const int base = (8 * j + (lane >> 3)) * 33 + 4 * (lane & 7);
        float4 v = make_float4(r0[base], r0[base + 1], r0[base + 2], r0[base + 3]);
        *(float4*)(crow + j * 256 + 4 * lane) = v;
    }
    // ---- phase 2: unpack A/B again, write f32 latents into r1, readback ----
#pragma unroll
    for (int s = 0; s < 16; ++s) {
        f16x2 pk1 = __builtin_bit_cast(f16x2, r1[wbase + s]);
        r1[wbase + s] = fmaf((float)pk1[0], lat0, (float)pk1[1]);
    }
#pragma unroll
    for (int j = 0; j < 4; ++j) {
        const int base = (8 * j + (lane >> 3)) * 33 + 4 * (lane & 7);
        float4 v = make_float4(r1[base], r1[base + 1], r1[base + 2], r1[base + 3]);
        *(float4*)(lrow + j * 256 + 4 * lane) = v;
    }

    // ---- per-wave loss partial ----
#pragma unroll
    for (int off = 32; off; off >>= 1) lacc += __shfl_down(lacc, off);
    if (lane == 0) partials[tid >> 6] = lacc;
#undef HSTEP
}

__global__ __launch_bounds__(1024) void bkt_loss(const float* __restrict__ partials, int n,
                                                 float* __restrict__ out_loss)
{
    __shared__ double sd[16];
    double s = 0.0;
    for (int i = threadIdx.x; i < n; i += 1024) s += (double)partials[i];
#pragma unroll
    for (int off = 32; off; off >>= 1) s += __shfl_down(s, off);
    if ((threadIdx.x & 63) == 0) sd[threadIdx.x >> 6] = s;
    __syncthreads();
    if (threadIdx.x == 0) {
        double t = 0.0;
#pragma unroll
        for (int k = 0; k < 16; ++k) t += sd[k];
        *out_loss = (float)(-t * 0.69314718055994530942 / ((double)BB * (double)TT));
    }
}

extern "C" void kernel_launch(void* const* d_in, const int* in_sizes, int n_in,
                              void* d_out, int out_size, void* d_ws, size_t ws_size,
                              hipStream_t stream)
{
    const float* x     = (const float*)d_in[0];
    const float* y     = (const float*)d_in[1];
    const float* Wxh   = (const float*)d_in[2];
    const float* Whh   = (const float*)d_in[3];
    const float* bh    = (const float*)d_in[4];
    const float* Wy    = (const float*)d_in[5];
    const float* by    = (const float*)d_in[6];
    const float* prior = (const float*)d_in[7];

    float* out      = (float*)d_out;
    float* corrects = out;
    float* latents  = out + (size_t)BB * TT;
    float* lossp    = out + (size_t)2 * BB * TT;

    float* partials = (float*)d_ws;                     // 16384 floats

    const int nblk = BB / 2;                            // 2 rows per 256-thread block
    bkt_fused<<<nblk, 256, 0, stream>>>(x, y, Wxh, Whh, bh, Wy, by, prior,
                                        corrects, latents, partials);
    bkt_loss<<<1, 1024, 0, stream>>>(partials, BB * 2, lossp);
}

// Round 24
// 63.078 us; speedup vs baseline: 1.0533x; 1.0533x over previous
//
#include <hip/hip_runtime.h>

#define BB 8192
#define TT 2048
#define WU  8    // h warmup steps: contraction ~0.4/step -> h err ~7e-4
// One wave = one ROW (64 lanes x 32-step windows). No cross-wave handoff, no
// __syncthreads. LDS region per wave: 64 rows x 33 words (one 32-step window per
// row) -- verified conflict-free family (write 2/bank, float4 readback 2/bank).
// (pg,cg) f16x2 -> LDS; (a,pl) f16x2 -> 32 regs; f32 (A,B) checkpoints every
// 4 steps bound the f16 latent-chain error to ~4e-3.

typedef __fp16 f16x2 __attribute__((ext_vector_type(2)));

__device__ __forceinline__ float sig2(float z) {
    return __builtin_amdgcn_rcpf(1.f + __builtin_amdgcn_exp2f(z));
}
__device__ __forceinline__ float sgpr(float v) {
    return __builtin_bit_cast(float, __builtin_amdgcn_readfirstlane(__builtin_bit_cast(int, v)));
}
__device__ __forceinline__ void ld16(float* d, const float* p) {
    *(float4*)(d)      = *(const float4*)(p);
    *(float4*)(d + 4)  = *(const float4*)(p + 4);
    *(float4*)(d + 8)  = *(const float4*)(p + 8);
    *(float4*)(d + 12) = *(const float4*)(p + 12);
}

// bound 3 (cap ~85): estimated live ~75 (apl32 + ck14 + yb16 + state). No-spill
// gate: FETCH ~66MB. Inflation -> estimate wrong -> revert to CLW=16 (R16).
__global__ __launch_bounds__(256, 3) void bkt_fused(
    const float* __restrict__ x, const float* __restrict__ y,
    const float* __restrict__ Wxh, const float* __restrict__ Whh,
    const float* __restrict__ bh, const float* __restrict__ Wy,
    const float* __restrict__ by, const float* __restrict__ prior,
    float* __restrict__ corrects, float* __restrict__ latents,
    float* __restrict__ partials)
{
    __shared__ float lds[4 * 64 * 33];                 // 33.8 KB: one region per wave
    const int tid  = blockIdx.x * 256 + threadIdx.x;
    const int lane = threadIdx.x & 63;                 // window id within the row
    const int wv   = threadIdx.x >> 6;                 // 0..3 = row in block
    const int row  = blockIdx.x * 4 + wv;
    float* r0 = &lds[wv * 2112];
    const int wbase = lane * 33;
    const float NL2E = -1.44269504088896340736f;

    // ---- weights -> SGPRs, pre-scaled for exp2-based sigmoid ----
    const float wh00=sgpr(Whh[0]*NL2E),  wh01=sgpr(Whh[1]*NL2E),
                wh02=sgpr(Whh[2]*NL2E),  wh03=sgpr(Whh[3]*NL2E),
                wh10=sgpr(Whh[4]*NL2E),  wh11=sgpr(Whh[5]*NL2E),
                wh12=sgpr(Whh[6]*NL2E),  wh13=sgpr(Whh[7]*NL2E),
                wh20=sgpr(Whh[8]*NL2E),  wh21=sgpr(Whh[9]*NL2E),
                wh22=sgpr(Whh[10]*NL2E), wh23=sgpr(Whh[11]*NL2E),
                wh30=sgpr(Whh[12]*NL2E), wh31=sgpr(Whh[13]*NL2E),
                wh32=sgpr(Whh[14]*NL2E), wh33=sgpr(Whh[15]*NL2E);
    const float wx0=sgpr(Wxh[0]*NL2E), wx1=sgpr(Wxh[1]*NL2E),
                wx2=sgpr(Wxh[2]*NL2E), wx3=sgpr(Wxh[3]*NL2E);
    const float bh0=sgpr(bh[0]*NL2E), bh1=sgpr(bh[1]*NL2E),
                bh2=sgpr(bh[2]*NL2E), bh3=sgpr(bh[3]*NL2E);
    const float wy00=sgpr(Wy[0]*NL2E),  wy01=sgpr(Wy[1]*NL2E),
                wy02=sgpr(Wy[2]*NL2E),  wy03=sgpr(Wy[3]*NL2E),
                wy10=sgpr(Wy[4]*NL2E),  wy11=sgpr(Wy[5]*NL2E),
                wy12=sgpr(Wy[6]*NL2E),  wy13=sgpr(Wy[7]*NL2E),
                wy20=sgpr(Wy[8]*NL2E),  wy21=sgpr(Wy[9]*NL2E),
                wy22=sgpr(Wy[10]*NL2E), wy23=sgpr(Wy[11]*NL2E),
                wy30=sgpr(Wy[12]*NL2E), wy31=sgpr(Wy[13]*NL2E),
                wy32=sgpr(Wy[14]*NL2E), wy33=sgpr(Wy[15]*NL2E);
    const float by0=sgpr(by[0]*NL2E), by1=sgpr(by[1]*NL2E),
                by2=sgpr(by[2]*NL2E), by3=sgpr(by[3]*NL2E);
    const float pr = sgpr(prior[0]);

#define HSTEP(xs)                                                                   \
    {                                                                               \
        float z0 = fmaf(h3,wh30,fmaf(h2,wh20,fmaf(h1,wh10,fmaf(h0,wh00,fmaf(xs,wx0,bh0))))); \
        float z1 = fmaf(h3,wh31,fmaf(h2,wh21,fmaf(h1,wh11,fmaf(h0,wh01,fmaf(xs,wx1,bh1))))); \
        float z2 = fmaf(h3,wh32,fmaf(h2,wh22,fmaf(h1,wh12,fmaf(h0,wh02,fmaf(xs,wx2,bh2))))); \
        float z3 = fmaf(h3,wh33,fmaf(h2,wh23,fmaf(h1,wh13,fmaf(h0,wh03,fmaf(xs,wx3,bh3))))); \
        h0 = sig2(z0); h1 = sig2(z1); h2 = sig2(z2); h3 = sig2(z3);                 \
    }

    const int t0 = lane * 32;
    const float* xrow = x + (size_t)row * TT;
    const float* yrow = y + (size_t)row * TT;
    float* crow = corrects + (size_t)row * TT;
    float* lrow = latents  + (size_t)row * TT;

    // ---- x loads up front (t0-8 is 32B-aligned) ----
    float xw[8], xb[16], xc[16];
    {
        const float* wp = xrow + (lane ? t0 - WU : 0);
        *(float4*)(xw)     = *(const float4*)(wp);
        *(float4*)(xw + 4) = *(const float4*)(wp + 4);
    }
    ld16(xb, xrow + t0);
    ld16(xc, xrow + t0 + 16);

    // ---- warmup: 8 HSTEPs (window 0 resets to exact h=0) ----
    float h0 = 0.f, h1 = 0.f, h2 = 0.f, h3 = 0.f;
    HSTEP(xw[0])  HSTEP(xw[1])  HSTEP(xw[2])  HSTEP(xw[3])
    HSTEP(xw[4])  HSTEP(xw[5])  HSTEP(xw[6])  HSTEP(xw[7])
    if (lane == 0) { h0 = h1 = h2 = h3 = 0.f; }

    // ---- single pass over 32 steps ----
    float apl[32];                  // f16x2 (a, pl) per step
    float Ack[7], Bck[7];           // f32 inclusive checkpoints after steps 3,7,..,27
    float Aacc = 1.f, Bacc = 0.f;
#define S1(s, DO_H, DO_CK)                                                          \
    {                                                                               \
        float zl = fmaf(h3,wy30,fmaf(h2,wy20,fmaf(h1,wy10,fmaf(h0,wy00,by0))));     \
        float zf = fmaf(h3,wy31,fmaf(h2,wy21,fmaf(h1,wy11,fmaf(h0,wy01,by1))));     \
        float zg = fmaf(h3,wy32,fmaf(h2,wy22,fmaf(h1,wy12,fmaf(h0,wy02,by2))));     \
        float zs = fmaf(h3,wy33,fmaf(h2,wy23,fmaf(h1,wy13,fmaf(h0,wy03,by3))));     \
        float pl = sig2(zl), pf = sig2(zf), pgs = sig2(zg), pss = sig2(zs);         \
        float a = (1.f - pf) - pl;                                                  \
        Bacc = fmaf(a, Bacc, pl);                                                   \
        Aacc *= a;                                                                  \
        f16x2 pk0 = __builtin_amdgcn_cvt_pkrtz(pgs, (1.f - pss) - pgs);             \
        f16x2 pk1 = __builtin_amdgcn_cvt_pkrtz(a, pl);                              \
        r0[wbase + (s)] = __builtin_bit_cast(float, pk0);                           \
        apl[s] = __builtin_bit_cast(float, pk1);                                    \
        DO_CK                                                                       \
        DO_H                                                                        \
    }
#define CK(k) Ack[k] = Aacc; Bck[k] = Bacc;
    S1(0,  HSTEP(xb[0]),  )  S1(1,  HSTEP(xb[1]),  )
    S1(2,  HSTEP(xb[2]),  )  S1(3,  HSTEP(xb[3]),  CK(0))
    S1(4,  HSTEP(xb[4]),  )  S1(5,  HSTEP(xb[5]),  )
    S1(6,  HSTEP(xb[6]),  )  S1(7,  HSTEP(xb[7]),  CK(1))
    S1(8,  HSTEP(xb[8]),  )  S1(9,  HSTEP(xb[9]),  )
    S1(10, HSTEP(xb[10]), )  S1(11, HSTEP(xb[11]), CK(2))
    S1(12, HSTEP(xb[12]), )  S1(13, HSTEP(xb[13]), )
    S1(14, HSTEP(xb[14]), )  S1(15, HSTEP(xb[15]), CK(3))
    S1(16, HSTEP(xc[0]),  )  S1(17, HSTEP(xc[1]),  )
    S1(18, HSTEP(xc[2]),  )  S1(19, HSTEP(xc[3]),  CK(4))
    S1(20, HSTEP(xc[4]),  )  S1(21, HSTEP(xc[5]),  )
    S1(22, HSTEP(xc[6]),  )  S1(23, HSTEP(xc[7]),  CK(5))
    S1(24, HSTEP(xc[8]),  )  S1(25, HSTEP(xc[9]),  )
    S1(26, HSTEP(xc[10]), )  S1(27, HSTEP(xc[11]), CK(6))
    S1(28, HSTEP(xc[12]), )  S1(29, HSTEP(xc[13]), )
    S1(30, HSTEP(xc[14]), )  S1(31, , )               // last h never consumed
#undef CK
#undef S1

    // ---- in-wave inclusive scan over the full row (64 windows) ----
    float As = Aacc, Bs = Bacc;
#pragma unroll
    for (int off = 1; off < 64; off <<= 1) {
        float Au = __shfl_up(As, off);
        float Bu = __shfl_up(Bs, off);
        if (lane >= off) { Bs = fmaf(As, Bu, Bs); As *= Au; }
    }
    const float Ae = __shfl_up(As, 1);
    const float Be = __shfl_up(Bs, 1);
    const float lat0 = (lane == 0) ? pr : fmaf(Ae, pr, Be);

    // ---- epilogue: c from (pg,cg); latp via f16 (a,pl) chain + f32 checkpoints.
    //      yb is REUSED for the second 16 steps (keeps live set under the cap). ----
    float yb[16];
    ld16(yb, yrow + t0);
    float lacc = 0.f, prod = 1.f, latp = lat0;
#define E(s, Y)                                                                     \
    {                                                                               \
        f16x2 pk0 = __builtin_bit_cast(f16x2, r0[wbase + (s)]);                     \
        f16x2 pk1 = __builtin_bit_cast(f16x2, apl[s]);                              \
        float cv = fmaf(latp, (float)pk0[1], (float)pk0[0]);                        \
        latp = fmaf((float)pk1[0], latp, (float)pk1[1]);                            \
        float cc  = fminf(fmaxf(cv, 1e-7f), 1.f - 1e-7f);                           \
        prod *= fmaf(Y[(s) & 15], fmaf(2.f, cc, -1.f), 1.f - cc);                   \
        r0[wbase + (s)] = cv;                                                       \
    }
#define RST(k) latp = fmaf(Ack[k], lat0, Bck[k]);
    E(0, yb)  E(1, yb)  E(2, yb)  E(3, yb)  RST(0)
    E(4, yb)  E(5, yb)  E(6, yb)  E(7, yb)  RST(1)
    lacc += __builtin_amdgcn_logf(prod); prod = 1.f;
    E(8, yb)  E(9, yb)  E(10, yb) E(11, yb) RST(2)
    E(12, yb) E(13, yb) E(14, yb) E(15, yb) RST(3)
    lacc += __builtin_amdgcn_logf(prod); prod = 1.f;
    ld16(yb, yrow + t0 + 16);                          // reuse buffer: second half
    E(16, yb) E(17, yb) E(18, yb) E(19, yb) RST(4)
    E(20, yb) E(21, yb) E(22, yb) E(23, yb) RST(5)
    lacc += __builtin_amdgcn_logf(prod); prod = 1.f;
    E(24, yb) E(25, yb) E(26, yb) E(27, yb) RST(6)
    E(28, yb) E(29, yb) E(30, yb) E(31, yb)
    lacc += __builtin_amdgcn_logf(prod);
#undef E
#undef RST

    // ---- corrects: transposed readback; each store instr = contiguous 1 KB ----
#pragma unroll
    for (int k = 0; k < 8; ++k) {
        const int base = (8 * k + (lane >> 3)) * 33 + 4 * (lane & 7);
        float4 v = make_float4(r0[base], r0[base + 1], r0[base + 2], r0[base + 3]);
        *(float4*)(crow + k * 256 + 4 * lane) = v;
    }
    // ---- phase 2: recompute latent trajectory into r0, readback ----
    {
        float latq = lat0;
#pragma unroll
        for (int s = 0; s < 4; ++s) {
            f16x2 pk1 = __builtin_bit_cast(f16x2, apl[s]);
            latq = fmaf((float)pk1[0], latq, (float)pk1[1]);
            r0[wbase + s] = latq;
        }
#define L4(s0, KPREV)                                                               \
        { latq = fmaf(Ack[KPREV], lat0, Bck[KPREV]);                                \
          _Pragma("unroll")                                                         \
          for (int s = (s0); s < (s0) + 4; ++s) {                                   \
              f16x2 pk1 = __builtin_bit_cast(f16x2, apl[s]);                        \
              latq = fmaf((float)pk1[0], latq, (float)pk1[1]);                      \
              r0[wbase + s] = latq;                                                 \
          } }
        L4(4, 0) L4(8, 1) L4(12, 2) L4(16, 3) L4(20, 4) L4(24, 5) L4(28, 6)
#undef L4
    }
#pragma unroll
    for (int k = 0; k < 8; ++k) {
        const int base = (8 * k + (lane >> 3)) * 33 + 4 * (lane & 7);
        float4 v = make_float4(r0[base], r0[base + 1], r0[base + 2], r0[base + 3]);
        *(float4*)(lrow + k * 256 + 4 * lane) = v;
    }

    // ---- per-wave loss partial ----
#pragma unroll
    for (int off = 32; off; off >>= 1) lacc += __shfl_down(lacc, off);
    if (lane == 0) partials[tid >> 6] = lacc;
#undef HSTEP
}

__global__ __launch_bounds__(1024) void bkt_loss(const float* __restrict__ partials, int n,
                                                 float* __restrict__ out_loss)
{
    __shared__ double sd[16];
    double s = 0.0;
    for (int i = threadIdx.x; i < n; i += 1024) s += (double)partials[i];
#pragma unroll
    for (int off = 32; off; off >>= 1) s += __shfl_down(s, off);
    if ((threadIdx.x & 63) == 0) sd[threadIdx.x >> 6] = s;
    __syncthreads();
    if (threadIdx.x == 0) {
        double t = 0.0;
#pragma unroll
        for (int k = 0; k < 16; ++k) t += sd[k];
        *out_loss = (float)(-t * 0.69314718055994530942 / ((double)BB * (double)TT));
    }
}

extern "C" void kernel_launch(void* const* d_in, const int* in_sizes, int n_in,
                              void* d_out, int out_size, void* d_ws, size_t ws_size,
                              hipStream_t stream)
{
    const float* x     = (const float*)d_in[0];
    const float* y     = (const float*)d_in[1];
    const float* Wxh   = (const float*)d_in[2];
    const float* Whh   = (const float*)d_in[3];
    const float* bh    = (const float*)d_in[4];
    const float* Wy    = (const float*)d_in[5];
    const float* by    = (const float*)d_in[6];
    const float* prior = (const float*)d_in[7];

    float* out      = (float*)d_out;
    float* corrects = out;
    float* latents  = out + (size_t)BB * TT;
    float* lossp    = out + (size_t)2 * BB * TT;

    float* partials = (float*)d_ws;                     // 8192 floats

    const int nblk = BB / 4;                            // 4 rows per 256-thread block
    bkt_fused<<<nblk, 256, 0, stream>>>(x, y, Wxh, Whh, bh, Wy, by, prior,
                                        corrects, latents, partials);
    bkt_loss<<<1, 1024, 0, stream>>>(partials, BB, lossp);
}